// Round 12
// baseline (436.576 us; speedup 1.0000x reference)
//
#include <hip/hip_runtime.h>
#include <hip/hip_bf16.h>

#define HIDN   64
#define NHEADS 8
#define DHEAD  8
#define NLAY   2
#define BB     4
#define SS     12
#define NNODE  512
#define NEDGE  8192
#define XELEMS (BB * SS * NNODE * 3)      // 73728
#define ROWS   (BB * SS * NNODE)          // 24576
#define SCALE  0.35355339059327373f       // 1/sqrt(8)
#define PSTR   38                         // P-buffer row stride (odd words -> no 4-way)

typedef unsigned short u16;
typedef unsigned int   u32;
typedef __attribute__((ext_vector_type(8))) short s8v;   // 8 bf16 (4 VGPRs)
typedef __attribute__((ext_vector_type(4))) float f4v;   // MFMA C/D

__device__ __forceinline__ float b2f(u16 u) {
    union { u32 i; float f; } c; c.i = ((u32)u) << 16; return c.f;
}
__device__ __forceinline__ u16 f2b(float f) {   // RNE float->bf16 bits
    union { float f; u32 i; } c; c.f = f;
    u32 r = c.i + 0x7FFFu + ((c.i >> 16) & 1u);
    return (u16)(r >> 16);
}

// -------- dtype detection: bf16 buffer decoded as bf16 has max|v|~4.5;
// -------- fp32 buffer halves decoded as bf16 hit |v|>1e30 / NaN w.p. ~1.
__global__ void detect_kernel(const u16* __restrict__ x, int* __restrict__ flag) {
    int i0 = blockIdx.x * 256 + threadIdx.x;
    int bad = 0;
    for (int i = i0; i < XELEMS; i += 64 * 256) {
        float v = fabsf(b2f(x[i]));
        if (!(v <= 100.f)) bad = 1;   // catches huge AND NaN
    }
    if (bad) atomicOr(flag, 1);       // flag=1 -> inputs are fp32
}

// ---------------- input staging: decode 17 tensors to fp32 per flag ----------
struct CvtArgs {
    const void* src[17];
    float*      dst[17];
    int         n[17];
};

__global__ void convert_kernel(CvtArgs a, const int* __restrict__ flagp) {
    int fl = *flagp;
    int y  = blockIdx.y;
    int t  = blockIdx.x * blockDim.x + threadIdx.x;
    if (t < a.n[y]) {
        float v = fl ? ((const float*)a.src[y])[t] : b2f(((const u16*)a.src[y])[t]);
        a.dst[y][t] = v;
    }
}

// ---------------- pack W[l][j][i] (fp32 staged) -> wT[l][i][192], bias[l][192]
__global__ void pack_kernel(const float* __restrict__ Wq, const float* __restrict__ bq,
                            const float* __restrict__ Wk, const float* __restrict__ bk,
                            const float* __restrict__ Wv, const float* __restrict__ bv,
                            float* __restrict__ wT, float* __restrict__ bp) {
    int l = blockIdx.y;
    int t = blockIdx.x * 256 + threadIdx.x;   // 0..12287
    int i = t / 192, j = t - i * 192;
    int c = j >> 6, cc = j & 63;
    const float* W = (c == 0) ? Wq : (c == 1) ? Wk : Wv;
    wT[l * 12288 + t] = W[l * 4096 + cc * 64 + i];
    if (i == 0) {
        const float* B = (c == 0) ? bq : (c == 1) ? bk : bv;
        bp[l * 192 + j] = B[l * 64 + cc];
    }
}

// ---------------- edge mask, transposed bitmask: maskT[n][m>>5] bit (m&31) ---
__global__ void scatter_mask_kernel(const int* __restrict__ ei, u32* __restrict__ maskT) {
    int e = blockIdx.x * blockDim.x + threadIdx.x;
    if (e < NEDGE) {
        int n = ei[e];          // query row
        int m = ei[NEDGE + e];  // key col
        atomicOr(&maskT[n * 16 + (m >> 5)], 1u << (m & 31));
    }
}

// ---------------- input projection: [B,S,N,3] @ WinT + b -> h [ROWS,64] ------
__global__ void input_proj_kernel(const float* __restrict__ x, const float* __restrict__ W,
                                  const float* __restrict__ b, float* __restrict__ h) {
    int t = blockIdx.x * blockDim.x + threadIdx.x;  // row*64 + j
    int row = t >> 6, j = t & 63;
    float x0 = x[row * 3];
    float x1 = x[row * 3 + 1];
    float x2 = x[row * 3 + 2];
    h[t] = b[j] + x0 * W[j * 3] + x1 * W[j * 3 + 1] + x2 * W[j * 3 + 2];
}

// ---------------- fused q/k/v GEMM (fp32 VALU, high-TLP) ---------------------
// block: 32 rows x 192 cols, 256 threads, 2x12 acc/thread, grid 768 = 3 blk/CU.
// spatial_layout=1: q/k/v BF16 [bs*8+hd][n][8]; q prescaled by 1/sqrt(8).
// spatial_layout=0: q/k/v fp32 row-major [row][64].
__global__ __launch_bounds__(256) void qkv_gemm_kernel(
    const float* __restrict__ h, const float* __restrict__ wT,
    const float* __restrict__ bias,
    float* __restrict__ q, float* __restrict__ k, float* __restrict__ v,
    u16* __restrict__ qb16, u16* __restrict__ kb16, u16* __restrict__ vb16,
    int spatial_layout) {
    __shared__ float hT[64][36];    // [i][r], 32 rows + pad
    __shared__ float wS[32][192];   // [i-half][j]
    __shared__ float bS[192];
    int t = threadIdx.x;
    int row0 = blockIdx.x * 32;
    // stage A transposed: 32 rows x 64 i (each thread: 1 row, 8 i)
    {
        int r = t & 31, ic = t >> 5;        // ic 0..7 -> i0 = ic*8
        const float* hp = h + (row0 + r) * 64 + ic * 8;
        float4 h0 = *(const float4*)hp;
        float4 h1 = *(const float4*)(hp + 4);
        int i = ic * 8;
        hT[i+0][r] = h0.x; hT[i+1][r] = h0.y; hT[i+2][r] = h0.z; hT[i+3][r] = h0.w;
        hT[i+4][r] = h1.x; hT[i+5][r] = h1.y; hT[i+6][r] = h1.z; hT[i+7][r] = h1.w;
    }
    // stage W phase 0 + bias
    {
        const float4* src = (const float4*)wT;
        float4* dst = (float4*)&wS[0][0];
#pragma unroll
        for (int c = 0; c < 6; ++c) dst[t + 256 * c] = src[t + 256 * c];
        if (t < 192) bS[t] = bias[t];
    }
    __syncthreads();
    int tc = t & 15, tr = t >> 4;
    int r0 = tc * 2, j0 = tr * 12;
    float acc[12][2];
#pragma unroll
    for (int j = 0; j < 12; ++j) {
        float bb = bS[j0 + j];
        acc[j][0] = bb; acc[j][1] = bb;
    }
#pragma unroll 4
    for (int i = 0; i < 32; ++i) {
        float2 a = *(const float2*)&hT[i][r0];
#pragma unroll
        for (int jj = 0; jj < 3; ++jj) {
            float4 w = *(const float4*)&wS[i][j0 + jj * 4];
            int jb = jj * 4;
            acc[jb+0][0] += w.x*a.x; acc[jb+0][1] += w.x*a.y;
            acc[jb+1][0] += w.y*a.x; acc[jb+1][1] += w.y*a.y;
            acc[jb+2][0] += w.z*a.x; acc[jb+2][1] += w.z*a.y;
            acc[jb+3][0] += w.w*a.x; acc[jb+3][1] += w.w*a.y;
        }
    }
    __syncthreads();
    // stage W phase 1
    {
        const float4* src = (const float4*)(wT + 32 * 192);
        float4* dst = (float4*)&wS[0][0];
#pragma unroll
        for (int c = 0; c < 6; ++c) dst[t + 256 * c] = src[t + 256 * c];
    }
    __syncthreads();
#pragma unroll 4
    for (int i = 0; i < 32; ++i) {
        float2 a = *(const float2*)&hT[32 + i][r0];
#pragma unroll
        for (int jj = 0; jj < 3; ++jj) {
            float4 w = *(const float4*)&wS[i][j0 + jj * 4];
            int jb = jj * 4;
            acc[jb+0][0] += w.x*a.x; acc[jb+0][1] += w.x*a.y;
            acc[jb+1][0] += w.y*a.x; acc[jb+1][1] += w.y*a.y;
            acc[jb+2][0] += w.z*a.x; acc[jb+2][1] += w.z*a.y;
            acc[jb+3][0] += w.w*a.x; acc[jb+3][1] += w.w*a.y;
        }
    }
    // epilogue
#pragma unroll
    for (int j = 0; j < 12; ++j) {
        int jj = j0 + j;
        int cc = jj & 63;
#pragma unroll
        for (int r = 0; r < 2; ++r) {
            int row = row0 + r0 + r;
            float val = acc[j][r];
            if (spatial_layout) {
                int bs = row >> 9, n = row & 511;
                int idx = ((bs * 8 + (cc >> 3)) * 512 + n) * 8 + (cc & 7);
                if (jj < 64)       qb16[idx] = f2b(val * SCALE);
                else if (jj < 128) kb16[idx] = f2b(val);
                else               vb16[idx] = f2b(val);
            } else {
                int idx = row * 64 + cc;
                float* dst = (jj < 64) ? q : (jj < 128) ? k : v;
                dst[idx] = val;
            }
        }
    }
}

// ---------------- spatial attention v7.1: MFMA flash, odd P-stride -----------
// grid 768 = (bs,hd,half); 256 threads (4 waves); wave owns 64 queries.
__global__ __launch_bounds__(256) void spatial_attn_kernel(
    const u16* __restrict__ qb, const u16* __restrict__ kb, const u16* __restrict__ vb,
    const u32* __restrict__ maskT, float* __restrict__ h) {
    __shared__ __align__(16) u16 Ks[NNODE * 8];      // [key][d]  8 KB
    __shared__ __align__(16) u16 Vs[9 * 520];        // [d|ones][key] stride 520
    __shared__ __align__(16) u32 Ms[16 * 256];       // [word][qlocal]  16 KB
    __shared__ __align__(16) u16 Pb[4][64 * PSTR];   // per-wave P, odd-word stride
    int bx = blockIdx.x;               // head*2 + half
    int head = bx >> 1, half = bx & 1;
    int bs = head >> 3, hd = head & 7;
    int base = head * (NNODE * 8);
    int t = threadIdx.x;
    // stage K rows
    {
        const uint4* kg = (const uint4*)(kb + base);
        uint4* kl = (uint4*)Ks;
        kl[t] = kg[t];
        kl[t + 256] = kg[t + 256];
    }
    // stage V transposed + ones row
    {
#pragma unroll
        for (int i = 0; i < 2; ++i) {
            int n = t + 256 * i;
            uint4 vr = *(const uint4*)(vb + base + n * 8);
            union { uint4 u; u16 s[8]; } V; V.u = vr;
#pragma unroll
            for (int d = 0; d < 8; ++d) Vs[d * 520 + n] = V.s[d];
            Vs[8 * 520 + n] = 0x3F80;   // 1.0bf16
        }
    }
    // stage mask transposed: Ms[w][n] = maskT[(half*256+n)*16 + w]
    {
        int qg0 = half * 256;
#pragma unroll
        for (int i = 0; i < 16; ++i) {
            int idx = t + 256 * i;      // 0..4095
            int n = idx >> 4, w = idx & 15;
            Ms[w * 256 + n] = maskT[(qg0 + n) * 16 + w];
        }
    }
    __syncthreads();
    int lane = t & 63;
    int wave = t >> 6;
    int c    = lane & 15;
    int quad = lane >> 4;
    int qloc0  = wave * 64;
    int qglob0 = half * 256 + qloc0;
    // Q fragments (B): lanes<16 hold Q[q][0..7]
    s8v Qf[4];
#pragma unroll
    for (int qt = 0; qt < 4; ++qt) {
        union { s8v v; uint4 u; } U; U.u = make_uint4(0, 0, 0, 0);
        if (lane < 16) U.u = *(const uint4*)(qb + base + (qglob0 + qt * 16 + lane) * 8);
        Qf[qt] = U.v;
    }
    f4v acc[4];
#pragma unroll
    for (int qt = 0; qt < 4; ++qt) acc[qt] = (f4v){0.f, 0.f, 0.f, 0.f};
    u16* Pw = &Pb[wave][0];
    for (int it = 0; it < 16; ++it) {
        int k0 = it * 32;
        s8v Kf[2];
#pragma unroll
        for (int kt = 0; kt < 2; ++kt) {
            union { s8v v; uint4 u; } U; U.u = make_uint4(0, 0, 0, 0);
            if (lane < 16) U.u = *(const uint4*)&Ks[(k0 + kt * 16 + lane) * 8];
            Kf[kt] = U.v;
        }
        union { s8v v; uint4 u; } Vu; Vu.u = make_uint4(0, 0, 0, 0);
        if (c <= 8) Vu.u = *(const uint4*)&Vs[c * 520 + k0 + quad * 8];
#pragma unroll
        for (int qt = 0; qt < 4; ++qt) {
            u32 wq = Ms[it * 256 + qloc0 + qt * 16 + c];
            int rbase = (qt * 16 + c) * PSTR;
#pragma unroll
            for (int kt = 0; kt < 2; ++kt) {
                f4v S = __builtin_amdgcn_mfma_f32_16x16x32_bf16(
                    Kf[kt], Qf[qt], (f4v){0.f, 0.f, 0.f, 0.f}, 0, 0, 0);
                u32 r[4];
#pragma unroll
                for (int reg = 0; reg < 4; ++reg) {
                    int bit = kt * 16 + quad * 4 + reg;
                    float bf = (float)((wq >> bit) & 1u);
                    float arg = fmaf(S[reg], 1.44269504f, fmaf(bf, 10000.f, -10000.f));
                    float e = exp2f(arg);                  // masked -> exactly 0
                    union { float f; u32 u; } E; E.f = e;
                    r[reg] = E.u + 0x7FFFu + ((E.u >> 16) & 1u);   // RNE bf16 hi16
                }
                u32 p0 = __builtin_amdgcn_perm(r[1], r[0], 0x07060302);
                u32 p1 = __builtin_amdgcn_perm(r[3], r[2], 0x07060302);
                *(uint2*)&Pw[rbase + kt * 16 + quad * 4] = make_uint2(p0, p1);
            }
        }
        __builtin_amdgcn_sched_barrier(0);   // keep P writes before A reads
#pragma unroll
        for (int qt = 0; qt < 4; ++qt) {
            int row = (qt * 16 + c) * PSTR;
            uint2 lo = *(const uint2*)&Pw[row + quad * 8];
            uint2 hi = *(const uint2*)&Pw[row + quad * 8 + 4];
            union { s8v v; uint4 u; } A; A.u = make_uint4(lo.x, lo.y, hi.x, hi.y);
            acc[qt] = __builtin_amdgcn_mfma_f32_16x16x32_bf16(A.v, Vu.v, acc[qt], 0, 0, 0);
        }
    }
    // epilogue: l lives in column 8; broadcast through per-wave LDS
    float* lb = (float*)Pw;   // 256 B reuse
    if (c == 8) {
#pragma unroll
        for (int qt = 0; qt < 4; ++qt)
#pragma unroll
            for (int reg = 0; reg < 4; ++reg)
                lb[qt * 16 + quad * 4 + reg] = acc[qt][reg];
    }
    __builtin_amdgcn_sched_barrier(0);
    if (c < 8) {
#pragma unroll
        for (int qt = 0; qt < 4; ++qt) {
#pragma unroll
            for (int reg = 0; reg < 4; ++reg) {
                int row = qt * 16 + quad * 4 + reg;
                float lv = lb[row];
                float o  = acc[qt][reg];
                if (lv == 0.f) {   // fully-masked row: uniform mean(v)
                    float s = 0.f;
                    for (int m = 0; m < NNODE; ++m) s += b2f(Vs[c * 520 + m]);
                    o = s; lv = (float)NNODE;
                }
                h[(bs * 512 + qglob0 + row) * 64 + hd * 8 + c] = o / lv;
            }
        }
    }
}

// ---------------- temporal attention: thread per (b,s,n,h), loop t (S=12) ----
__global__ __launch_bounds__(256) void temporal_attn_kernel(
    const float* __restrict__ q, const float* __restrict__ k, const float* __restrict__ v,
    float* __restrict__ h) {
    int t    = blockIdx.x * blockDim.x + threadIdx.x;
    int hd   = t & 7;
    int n    = (t >> 3) & (NNODE - 1);
    int rest = t >> 12;  // b*S + sq
    int b    = rest / SS;
    const float* qp = q + (rest * NNODE + n) * HIDN + hd * DHEAD;
    float4 qa = *(const float4*)qp;
    float4 qc = *(const float4*)(qp + 4);
    const float* kbase = k + (b * SS * NNODE + n) * HIDN + hd * DHEAD;
    const float* vbase = v + (b * SS * NNODE + n) * HIDN + hd * DHEAD;
    float s[SS];
#pragma unroll
    for (int tt = 0; tt < SS; ++tt) {
        const float* kp = kbase + tt * (NNODE * HIDN);
        float4 ka = *(const float4*)kp;
        float4 kc = *(const float4*)(kp + 4);
        s[tt] = (qa.x * ka.x + qa.y * ka.y + qa.z * ka.z + qa.w * ka.w +
                 qc.x * kc.x + qc.y * kc.y + qc.z * kc.z + qc.w * kc.w) * SCALE;
    }
    float mx = s[0];
#pragma unroll
    for (int tt = 1; tt < SS; ++tt) mx = fmaxf(mx, s[tt]);
    float l = 0.f;
#pragma unroll
    for (int tt = 0; tt < SS; ++tt) { s[tt] = __expf(s[tt] - mx); l += s[tt]; }
    float a0 = 0.f, a1 = 0.f, a2 = 0.f, a3 = 0.f, a4 = 0.f, a5 = 0.f, a6 = 0.f, a7 = 0.f;
#pragma unroll
    for (int tt = 0; tt < SS; ++tt) {
        const float* vp = vbase + tt * (NNODE * HIDN);
        float4 va = *(const float4*)vp;
        float4 vc = *(const float4*)(vp + 4);
        float e = s[tt];
        a0 += e * va.x; a1 += e * va.y; a2 += e * va.z; a3 += e * va.w;
        a4 += e * vc.x; a5 += e * vc.y; a6 += e * vc.z; a7 += e * vc.w;
    }
    float inv = 1.f / l;
    float* op = h + (rest * NNODE + n) * HIDN + hd * DHEAD;
    *(float4*)op       = make_float4(a0 * inv, a1 * inv, a2 * inv, a3 * inv);
    *(float4*)(op + 4) = make_float4(a4 * inv, a5 * inv, a6 * inv, a7 * inv);
}

// ---------------- output projection: h[:, S-1] @ WoutT + bout ----------------
__global__ void out_proj_kernel(const float* __restrict__ h, const float* __restrict__ W,
                                const float* __restrict__ b, void* __restrict__ out,
                                const int* __restrict__ flagp) {
    int t = blockIdx.x * blockDim.x + threadIdx.x;
    if (t >= BB * NNODE * 3) return;
    int c  = t % 3;
    int bn = t / 3;
    int n  = bn & (NNODE - 1);
    int bb = bn >> 9;
    const float* hp = h + ((bb * SS + (SS - 1)) * NNODE + n) * HIDN;
    const float* wp = W + c * HIDN;
    float a = b[c];
#pragma unroll
    for (int i = 0; i < HIDN; i += 4) {
        float4 h4 = *(const float4*)(hp + i);
        float4 w4 = *(const float4*)(wp + i);
        a += h4.x * w4.x + h4.y * w4.y + h4.z * w4.z + h4.w * w4.w;
    }
    if (*flagp) ((float*)out)[t] = a;
    else        ((__hip_bfloat16*)out)[t] = __float2bfloat16(a);
}

extern "C" void kernel_launch(void* const* d_in, const int* in_sizes, int n_in,
                              void* d_out, int out_size, void* d_ws, size_t ws_size,
                              hipStream_t stream) {
    const int* ei = (const int*)d_in[1];

    float* ws = (float*)d_ws;
    int*   flag   = (int*)ws;              // 64 floats reserved
    float* Win_f  = ws + 64;
    float* bin_f  = ws + 256;
    float* Wqs_f  = ws + 320;
    float* bqs_f  = ws + 8512;
    float* Wks_f  = ws + 8640;
    float* bks_f  = ws + 16832;
    float* Wvs_f  = ws + 16960;
    float* bvs_f  = ws + 25152;
    float* Wqt_f  = ws + 25280;
    float* bqt_f  = ws + 33472;
    float* Wkt_f  = ws + 33600;
    float* bkt_f  = ws + 41792;
    float* Wvt_f  = ws + 41920;
    float* bvt_f  = ws + 50112;
    float* Wout_f = ws + 50240;
    float* bout_f = ws + 50432;
    float* xf     = ws + 50496;            // 73728
    u32*   maskT  = (u32*)(ws + 124224);   // 8192 u32
    float* wTs    = ws + 132416;           // 2*12288
    float* wTt    = ws + 156992;           // 2*12288
    float* bsp    = ws + 181568;           // 2*192
    float* btp    = ws + 181952;           // 2*192
    float* hbuf   = ws + 182336;           // 1572864 each
    float* qbuf   = hbuf + ROWS * HIDN;
    float* kbuf   = qbuf + ROWS * HIDN;
    float* vbuf   = kbuf + ROWS * HIDN;
    u16*   qb16   = (u16*)qbuf;            // alias: spatial q bf16 (prescaled)
    u16*   kb16   = (u16*)kbuf;            // alias: spatial K bf16
    u16*   vb16   = (u16*)vbuf;            // alias: spatial V bf16
    // total ws use ~25.9 MB

    CvtArgs ca;
    const void* srcs[17] = {d_in[2], d_in[3], d_in[4], d_in[5], d_in[6], d_in[7],
                            d_in[8], d_in[9], d_in[10], d_in[11], d_in[12], d_in[13],
                            d_in[14], d_in[15], d_in[16], d_in[17], d_in[0]};
    float* dsts[17] = {Win_f, bin_f, Wqs_f, bqs_f, Wks_f, bks_f, Wvs_f, bvs_f,
                       Wqt_f, bqt_f, Wkt_f, bkt_f, Wvt_f, bvt_f, Wout_f, bout_f, xf};
    int    ns[17]   = {192, 64, 8192, 128, 8192, 128, 8192, 128,
                       8192, 128, 8192, 128, 8192, 128, 192, 3, XELEMS};
    for (int i = 0; i < 17; ++i) { ca.src[i] = srcs[i]; ca.dst[i] = dsts[i]; ca.n[i] = ns[i]; }

    (void)hipMemsetAsync(flag, 0, sizeof(int), stream);
    (void)hipMemsetAsync(maskT, 0, 8192 * sizeof(u32), stream);
    detect_kernel<<<64, 256, 0, stream>>>((const u16*)d_in[0], flag);
    convert_kernel<<<dim3((XELEMS + 255) / 256, 17), 256, 0, stream>>>(ca, flag);
    pack_kernel<<<dim3(48, 2), 256, 0, stream>>>(Wqs_f, bqs_f, Wks_f, bks_f, Wvs_f, bvs_f, wTs, bsp);
    pack_kernel<<<dim3(48, 2), 256, 0, stream>>>(Wqt_f, bqt_f, Wkt_f, bkt_f, Wvt_f, bvt_f, wTt, btp);
    scatter_mask_kernel<<<NEDGE / 256, 256, 0, stream>>>(ei, maskT);
    input_proj_kernel<<<ROWS * HIDN / 256, 256, 0, stream>>>(xf, Win_f, bin_f, hbuf);

    const int GEMM_BLOCKS = ROWS / 32;                       // 768
    const int ATTN_BLOCKS = BB * SS * NHEADS * NNODE / 256;  // 768 (temporal)
    for (int l = 0; l < NLAY; ++l) {
        // spatial
        qkv_gemm_kernel<<<GEMM_BLOCKS, 256, 0, stream>>>(
            hbuf, wTs + l * 12288, bsp + l * 192, qbuf, kbuf, vbuf,
            qb16, kb16, vb16, 1);
        spatial_attn_kernel<<<BB * SS * NHEADS * 2, 256, 0, stream>>>(
            qb16, kb16, vb16, maskT, hbuf);
        // temporal
        qkv_gemm_kernel<<<GEMM_BLOCKS, 256, 0, stream>>>(
            hbuf, wTt + l * 12288, btp + l * 192, qbuf, kbuf, vbuf,
            qb16, kb16, vb16, 0);
        temporal_attn_kernel<<<ATTN_BLOCKS, 256, 0, stream>>>(qbuf, kbuf, vbuf, hbuf);
    }
    out_proj_kernel<<<(BB * NNODE * 3 + 255) / 256, 256, 0, stream>>>(
        hbuf, Wout_f, bout_f, d_out, flag);
}

// Round 13
// 315.476 us; speedup vs baseline: 1.3839x; 1.3839x over previous
//
#include <hip/hip_runtime.h>
#include <hip/hip_bf16.h>

#define HIDN   64
#define NHEADS 8
#define DHEAD  8
#define NLAY   2
#define BB     4
#define SS     12
#define NNODE  512
#define NEDGE  8192
#define XELEMS (BB * SS * NNODE * 3)      // 73728
#define ROWS   (BB * SS * NNODE)          // 24576
#define SCALE  0.35355339059327373f       // 1/sqrt(8)
#define PSTR   36                         // P row stride u16; MUST be mult of 4 (b64 align)

typedef unsigned short u16;
typedef unsigned int   u32;
typedef __attribute__((ext_vector_type(8))) short s8v;   // 8 bf16 (4 VGPRs)
typedef __attribute__((ext_vector_type(4))) float f4v;   // MFMA C/D

__device__ __forceinline__ float b2f(u16 u) {
    union { u32 i; float f; } c; c.i = ((u32)u) << 16; return c.f;
}
__device__ __forceinline__ u16 f2b(float f) {   // RNE float->bf16 bits
    union { float f; u32 i; } c; c.f = f;
    u32 r = c.i + 0x7FFFu + ((c.i >> 16) & 1u);
    return (u16)(r >> 16);
}

// -------- dtype detection: bf16 buffer decoded as bf16 has max|v|~4.5;
// -------- fp32 buffer halves decoded as bf16 hit |v|>1e30 / NaN w.p. ~1.
__global__ void detect_kernel(const u16* __restrict__ x, int* __restrict__ flag) {
    int i0 = blockIdx.x * 256 + threadIdx.x;
    int bad = 0;
    for (int i = i0; i < XELEMS; i += 64 * 256) {
        float v = fabsf(b2f(x[i]));
        if (!(v <= 100.f)) bad = 1;   // catches huge AND NaN
    }
    if (bad) atomicOr(flag, 1);       // flag=1 -> inputs are fp32
}

// ---------------- input staging: decode 17 tensors to fp32 per flag ----------
struct CvtArgs {
    const void* src[17];
    float*      dst[17];
    int         n[17];
};

__global__ void convert_kernel(CvtArgs a, const int* __restrict__ flagp) {
    int fl = *flagp;
    int y  = blockIdx.y;
    int t  = blockIdx.x * blockDim.x + threadIdx.x;
    if (t < a.n[y]) {
        float v = fl ? ((const float*)a.src[y])[t] : b2f(((const u16*)a.src[y])[t]);
        a.dst[y][t] = v;
    }
}

// ---------------- pack W[l][j][i] (fp32 staged) -> wT[l][i][192], bias[l][192]
__global__ void pack_kernel(const float* __restrict__ Wq, const float* __restrict__ bq,
                            const float* __restrict__ Wk, const float* __restrict__ bk,
                            const float* __restrict__ Wv, const float* __restrict__ bv,
                            float* __restrict__ wT, float* __restrict__ bp) {
    int l = blockIdx.y;
    int t = blockIdx.x * 256 + threadIdx.x;   // 0..12287
    int i = t / 192, j = t - i * 192;
    int c = j >> 6, cc = j & 63;
    const float* W = (c == 0) ? Wq : (c == 1) ? Wk : Wv;
    wT[l * 12288 + t] = W[l * 4096 + cc * 64 + i];
    if (i == 0) {
        const float* B = (c == 0) ? bq : (c == 1) ? bk : bv;
        bp[l * 192 + j] = B[l * 64 + cc];
    }
}

// ---------------- edge mask, transposed bitmask: maskT[n][m>>5] bit (m&31) ---
__global__ void scatter_mask_kernel(const int* __restrict__ ei, u32* __restrict__ maskT) {
    int e = blockIdx.x * blockDim.x + threadIdx.x;
    if (e < NEDGE) {
        int n = ei[e];          // query row
        int m = ei[NEDGE + e];  // key col
        atomicOr(&maskT[n * 16 + (m >> 5)], 1u << (m & 31));
    }
}

// ---------------- input projection: [B,S,N,3] @ WinT + b -> h [ROWS,64] ------
__global__ void input_proj_kernel(const float* __restrict__ x, const float* __restrict__ W,
                                  const float* __restrict__ b, float* __restrict__ h) {
    int t = blockIdx.x * blockDim.x + threadIdx.x;  // row*64 + j
    int row = t >> 6, j = t & 63;
    float x0 = x[row * 3];
    float x1 = x[row * 3 + 1];
    float x2 = x[row * 3 + 2];
    h[t] = b[j] + x0 * W[j * 3] + x1 * W[j * 3 + 1] + x2 * W[j * 3 + 2];
}

// ---------------- fused q/k/v GEMM (fp32 VALU, high-TLP) ---------------------
// block: 32 rows x 192 cols, 256 threads, 2x12 acc/thread, grid 768 = 3 blk/CU.
// spatial_layout=1: q/k/v BF16 [bs*8+hd][n][8]; q prescaled by 1/sqrt(8).
// spatial_layout=0: q/k/v fp32 row-major [row][64].
__global__ __launch_bounds__(256) void qkv_gemm_kernel(
    const float* __restrict__ h, const float* __restrict__ wT,
    const float* __restrict__ bias,
    float* __restrict__ q, float* __restrict__ k, float* __restrict__ v,
    u16* __restrict__ qb16, u16* __restrict__ kb16, u16* __restrict__ vb16,
    int spatial_layout) {
    __shared__ float hT[64][36];    // [i][r], 32 rows + pad
    __shared__ float wS[32][192];   // [i-half][j]
    __shared__ float bS[192];
    int t = threadIdx.x;
    int row0 = blockIdx.x * 32;
    // stage A transposed: 32 rows x 64 i (each thread: 1 row, 8 i)
    {
        int r = t & 31, ic = t >> 5;        // ic 0..7 -> i0 = ic*8
        const float* hp = h + (row0 + r) * 64 + ic * 8;
        float4 h0 = *(const float4*)hp;
        float4 h1 = *(const float4*)(hp + 4);
        int i = ic * 8;
        hT[i+0][r] = h0.x; hT[i+1][r] = h0.y; hT[i+2][r] = h0.z; hT[i+3][r] = h0.w;
        hT[i+4][r] = h1.x; hT[i+5][r] = h1.y; hT[i+6][r] = h1.z; hT[i+7][r] = h1.w;
    }
    // stage W phase 0 + bias
    {
        const float4* src = (const float4*)wT;
        float4* dst = (float4*)&wS[0][0];
#pragma unroll
        for (int c = 0; c < 6; ++c) dst[t + 256 * c] = src[t + 256 * c];
        if (t < 192) bS[t] = bias[t];
    }
    __syncthreads();
    int tc = t & 15, tr = t >> 4;
    int r0 = tc * 2, j0 = tr * 12;
    float acc[12][2];
#pragma unroll
    for (int j = 0; j < 12; ++j) {
        float bb = bS[j0 + j];
        acc[j][0] = bb; acc[j][1] = bb;
    }
#pragma unroll 4
    for (int i = 0; i < 32; ++i) {
        float2 a = *(const float2*)&hT[i][r0];
#pragma unroll
        for (int jj = 0; jj < 3; ++jj) {
            float4 w = *(const float4*)&wS[i][j0 + jj * 4];
            int jb = jj * 4;
            acc[jb+0][0] += w.x*a.x; acc[jb+0][1] += w.x*a.y;
            acc[jb+1][0] += w.y*a.x; acc[jb+1][1] += w.y*a.y;
            acc[jb+2][0] += w.z*a.x; acc[jb+2][1] += w.z*a.y;
            acc[jb+3][0] += w.w*a.x; acc[jb+3][1] += w.w*a.y;
        }
    }
    __syncthreads();
    // stage W phase 1
    {
        const float4* src = (const float4*)(wT + 32 * 192);
        float4* dst = (float4*)&wS[0][0];
#pragma unroll
        for (int c = 0; c < 6; ++c) dst[t + 256 * c] = src[t + 256 * c];
    }
    __syncthreads();
#pragma unroll 4
    for (int i = 0; i < 32; ++i) {
        float2 a = *(const float2*)&hT[32 + i][r0];
#pragma unroll
        for (int jj = 0; jj < 3; ++jj) {
            float4 w = *(const float4*)&wS[i][j0 + jj * 4];
            int jb = jj * 4;
            acc[jb+0][0] += w.x*a.x; acc[jb+0][1] += w.x*a.y;
            acc[jb+1][0] += w.y*a.x; acc[jb+1][1] += w.y*a.y;
            acc[jb+2][0] += w.z*a.x; acc[jb+2][1] += w.z*a.y;
            acc[jb+3][0] += w.w*a.x; acc[jb+3][1] += w.w*a.y;
        }
    }
    // epilogue
#pragma unroll
    for (int j = 0; j < 12; ++j) {
        int jj = j0 + j;
        int cc = jj & 63;
#pragma unroll
        for (int r = 0; r < 2; ++r) {
            int row = row0 + r0 + r;
            float val = acc[j][r];
            if (spatial_layout) {
                int bs = row >> 9, n = row & 511;
                int idx = ((bs * 8 + (cc >> 3)) * 512 + n) * 8 + (cc & 7);
                if (jj < 64)       qb16[idx] = f2b(val * SCALE);
                else if (jj < 128) kb16[idx] = f2b(val);
                else               vb16[idx] = f2b(val);
            } else {
                int idx = row * 64 + cc;
                float* dst = (jj < 64) ? q : (jj < 128) ? k : v;
                dst[idx] = val;
            }
        }
    }
}

// ---------------- spatial attention v7.2: MFMA flash, HW-exp -----------------
// grid 768 = (bs,hd,half); 256 threads (4 waves); wave owns 64 queries.
// S^T = K.Q^T (16x16x32 bf16); e = masked ? __expf(S) : 0 (HW v_exp_f32);
// P->LDS->A-frag; O = P.[V|1] gives l in col 8 free. q prescaled.
__global__ __launch_bounds__(256) void spatial_attn_kernel(
    const u16* __restrict__ qb, const u16* __restrict__ kb, const u16* __restrict__ vb,
    const u32* __restrict__ maskT, float* __restrict__ h) {
    __shared__ __align__(16) u16 Ks[NNODE * 8];      // [key][d]  8 KB
    __shared__ __align__(16) u16 Vs[9 * 520];        // [d|ones][key] stride 520
    __shared__ __align__(16) u32 Ms[16 * 256];       // [word][qlocal]  16 KB
    __shared__ __align__(16) u16 Pb[4][64 * PSTR];   // per-wave P [q][key] stride 36
    int bx = blockIdx.x;               // head*2 + half
    int head = bx >> 1, half = bx & 1;
    int bs = head >> 3, hd = head & 7;
    int base = head * (NNODE * 8);
    int t = threadIdx.x;
    // stage K rows
    {
        const uint4* kg = (const uint4*)(kb + base);
        uint4* kl = (uint4*)Ks;
        kl[t] = kg[t];
        kl[t + 256] = kg[t + 256];
    }
    // stage V transposed + ones row
    {
#pragma unroll
        for (int i = 0; i < 2; ++i) {
            int n = t + 256 * i;
            uint4 vr = *(const uint4*)(vb + base + n * 8);
            union { uint4 u; u16 s[8]; } V; V.u = vr;
#pragma unroll
            for (int d = 0; d < 8; ++d) Vs[d * 520 + n] = V.s[d];
            Vs[8 * 520 + n] = 0x3F80;   // 1.0bf16
        }
    }
    // stage mask transposed: Ms[w][n] = maskT[(half*256+n)*16 + w]
    {
        int qg0 = half * 256;
#pragma unroll
        for (int i = 0; i < 16; ++i) {
            int idx = t + 256 * i;      // 0..4095
            int n = idx >> 4, w = idx & 15;
            Ms[w * 256 + n] = maskT[(qg0 + n) * 16 + w];
        }
    }
    __syncthreads();
    int lane = t & 63;
    int wave = t >> 6;
    int c    = lane & 15;
    int quad = lane >> 4;
    int qloc0  = wave * 64;
    int qglob0 = half * 256 + qloc0;
    // Q fragments (B): lanes<16 hold Q[q][0..7]
    s8v Qf[4];
#pragma unroll
    for (int qt = 0; qt < 4; ++qt) {
        union { s8v v; uint4 u; } U; U.u = make_uint4(0, 0, 0, 0);
        if (lane < 16) U.u = *(const uint4*)(qb + base + (qglob0 + qt * 16 + lane) * 8);
        Qf[qt] = U.v;
    }
    f4v acc[4];
#pragma unroll
    for (int qt = 0; qt < 4; ++qt) acc[qt] = (f4v){0.f, 0.f, 0.f, 0.f};
    u16* Pw = &Pb[wave][0];
    for (int it = 0; it < 16; ++it) {
        int k0 = it * 32;
        s8v Kf[2];
#pragma unroll
        for (int kt = 0; kt < 2; ++kt) {
            union { s8v v; uint4 u; } U; U.u = make_uint4(0, 0, 0, 0);
            if (lane < 16) U.u = *(const uint4*)&Ks[(k0 + kt * 16 + lane) * 8];
            Kf[kt] = U.v;
        }
        union { s8v v; uint4 u; } Vu; Vu.u = make_uint4(0, 0, 0, 0);
        if (c <= 8) Vu.u = *(const uint4*)&Vs[c * 520 + k0 + quad * 8];
#pragma unroll
        for (int qt = 0; qt < 4; ++qt) {
            u32 wq = Ms[it * 256 + qloc0 + qt * 16 + c];
            int rbase = (qt * 16 + c) * PSTR;
#pragma unroll
            for (int kt = 0; kt < 2; ++kt) {
                f4v S = __builtin_amdgcn_mfma_f32_16x16x32_bf16(
                    Kf[kt], Qf[qt], (f4v){0.f, 0.f, 0.f, 0.f}, 0, 0, 0);
                u32 r[4];
#pragma unroll
                for (int reg = 0; reg < 4; ++reg) {
                    int bit = kt * 16 + quad * 4 + reg;
                    // HW v_exp path (proven R2-R6); masked -> exactly 0
                    float e = ((wq >> bit) & 1u) ? __expf(S[reg]) : 0.f;
                    union { float f; u32 u; } E; E.f = e;
                    r[reg] = E.u + 0x7FFFu + ((E.u >> 16) & 1u);   // RNE bf16 hi16
                }
                u32 p0 = __builtin_amdgcn_perm(r[1], r[0], 0x07060302);
                u32 p1 = __builtin_amdgcn_perm(r[3], r[2], 0x07060302);
                *(uint2*)&Pw[rbase + kt * 16 + quad * 4] = make_uint2(p0, p1);
            }
        }
        __builtin_amdgcn_sched_barrier(0);   // keep P writes before A reads
#pragma unroll
        for (int qt = 0; qt < 4; ++qt) {
            int row = (qt * 16 + c) * PSTR;
            uint2 lo = *(const uint2*)&Pw[row + quad * 8];
            uint2 hi = *(const uint2*)&Pw[row + quad * 8 + 4];
            union { s8v v; uint4 u; } A; A.u = make_uint4(lo.x, lo.y, hi.x, hi.y);
            acc[qt] = __builtin_amdgcn_mfma_f32_16x16x32_bf16(A.v, Vu.v, acc[qt], 0, 0, 0);
        }
    }
    // epilogue: l lives in column 8; broadcast through per-wave LDS
    float* lb = (float*)Pw;   // 256 B reuse
    if (c == 8) {
#pragma unroll
        for (int qt = 0; qt < 4; ++qt)
#pragma unroll
            for (int reg = 0; reg < 4; ++reg)
                lb[qt * 16 + quad * 4 + reg] = acc[qt][reg];
    }
    __builtin_amdgcn_sched_barrier(0);
    if (c < 8) {
#pragma unroll
        for (int qt = 0; qt < 4; ++qt) {
#pragma unroll
            for (int reg = 0; reg < 4; ++reg) {
                int row = qt * 16 + quad * 4 + reg;
                float lv = lb[row];
                float o  = acc[qt][reg];
                if (lv == 0.f) {   // fully-masked row: uniform mean(v)
                    float s = 0.f;
                    for (int m = 0; m < NNODE; ++m) s += b2f(Vs[c * 520 + m]);
                    o = s; lv = (float)NNODE;
                }
                h[(bs * 512 + qglob0 + row) * 64 + hd * 8 + c] = o / lv;
            }
        }
    }
}

// ---------------- temporal attention: thread per (b,s,n,h), loop t (S=12) ----
__global__ __launch_bounds__(256) void temporal_attn_kernel(
    const float* __restrict__ q, const float* __restrict__ k, const float* __restrict__ v,
    float* __restrict__ h) {
    int t    = blockIdx.x * blockDim.x + threadIdx.x;
    int hd   = t & 7;
    int n    = (t >> 3) & (NNODE - 1);
    int rest = t >> 12;  // b*S + sq
    int b    = rest / SS;
    const float* qp = q + (rest * NNODE + n) * HIDN + hd * DHEAD;
    float4 qa = *(const float4*)qp;
    float4 qc = *(const float4*)(qp + 4);
    const float* kbase = k + (b * SS * NNODE + n) * HIDN + hd * DHEAD;
    const float* vbase = v + (b * SS * NNODE + n) * HIDN + hd * DHEAD;
    float s[SS];
#pragma unroll
    for (int tt = 0; tt < SS; ++tt) {
        const float* kp = kbase + tt * (NNODE * HIDN);
        float4 ka = *(const float4*)kp;
        float4 kc = *(const float4*)(kp + 4);
        s[tt] = (qa.x * ka.x + qa.y * ka.y + qa.z * ka.z + qa.w * ka.w +
                 qc.x * kc.x + qc.y * kc.y + qc.z * kc.z + qc.w * kc.w) * SCALE;
    }
    float mx = s[0];
#pragma unroll
    for (int tt = 1; tt < SS; ++tt) mx = fmaxf(mx, s[tt]);
    float l = 0.f;
#pragma unroll
    for (int tt = 0; tt < SS; ++tt) { s[tt] = __expf(s[tt] - mx); l += s[tt]; }
    float a0 = 0.f, a1 = 0.f, a2 = 0.f, a3 = 0.f, a4 = 0.f, a5 = 0.f, a6 = 0.f, a7 = 0.f;
#pragma unroll
    for (int tt = 0; tt < SS; ++tt) {
        const float* vp = vbase + tt * (NNODE * HIDN);
        float4 va = *(const float4*)vp;
        float4 vc = *(const float4*)(vp + 4);
        float e = s[tt];
        a0 += e * va.x; a1 += e * va.y; a2 += e * va.z; a3 += e * va.w;
        a4 += e * vc.x; a5 += e * vc.y; a6 += e * vc.z; a7 += e * vc.w;
    }
    float inv = 1.f / l;
    float* op = h + (rest * NNODE + n) * HIDN + hd * DHEAD;
    *(float4*)op       = make_float4(a0 * inv, a1 * inv, a2 * inv, a3 * inv);
    *(float4*)(op + 4) = make_float4(a4 * inv, a5 * inv, a6 * inv, a7 * inv);
}

// ---------------- output projection: h[:, S-1] @ WoutT + bout ----------------
__global__ void out_proj_kernel(const float* __restrict__ h, const float* __restrict__ W,
                                const float* __restrict__ b, void* __restrict__ out,
                                const int* __restrict__ flagp) {
    int t = blockIdx.x * blockDim.x + threadIdx.x;
    if (t >= BB * NNODE * 3) return;
    int c  = t % 3;
    int bn = t / 3;
    int n  = bn & (NNODE - 1);
    int bb = bn >> 9;
    const float* hp = h + ((bb * SS + (SS - 1)) * NNODE + n) * HIDN;
    const float* wp = W + c * HIDN;
    float a = b[c];
#pragma unroll
    for (int i = 0; i < HIDN; i += 4) {
        float4 h4 = *(const float4*)(hp + i);
        float4 w4 = *(const float4*)(wp + i);
        a += h4.x * w4.x + h4.y * w4.y + h4.z * w4.z + h4.w * w4.w;
    }
    if (*flagp) ((float*)out)[t] = a;
    else        ((__hip_bfloat16*)out)[t] = __float2bfloat16(a);
}

extern "C" void kernel_launch(void* const* d_in, const int* in_sizes, int n_in,
                              void* d_out, int out_size, void* d_ws, size_t ws_size,
                              hipStream_t stream) {
    const int* ei = (const int*)d_in[1];

    float* ws = (float*)d_ws;
    int*   flag   = (int*)ws;              // 64 floats reserved
    float* Win_f  = ws + 64;
    float* bin_f  = ws + 256;
    float* Wqs_f  = ws + 320;
    float* bqs_f  = ws + 8512;
    float* Wks_f  = ws + 8640;
    float* bks_f  = ws + 16832;
    float* Wvs_f  = ws + 16960;
    float* bvs_f  = ws + 25152;
    float* Wqt_f  = ws + 25280;
    float* bqt_f  = ws + 33472;
    float* Wkt_f  = ws + 33600;
    float* bkt_f  = ws + 41792;
    float* Wvt_f  = ws + 41920;
    float* bvt_f  = ws + 50112;
    float* Wout_f = ws + 50240;
    float* bout_f = ws + 50432;
    float* xf     = ws + 50496;            // 73728
    u32*   maskT  = (u32*)(ws + 124224);   // 8192 u32
    float* wTs    = ws + 132416;           // 2*12288
    float* wTt    = ws + 156992;           // 2*12288
    float* bsp    = ws + 181568;           // 2*192
    float* btp    = ws + 181952;           // 2*192
    float* hbuf   = ws + 182336;           // 1572864 each
    float* qbuf   = hbuf + ROWS * HIDN;
    float* kbuf   = qbuf + ROWS * HIDN;
    float* vbuf   = kbuf + ROWS * HIDN;
    u16*   qb16   = (u16*)qbuf;            // alias: spatial q bf16 (prescaled)
    u16*   kb16   = (u16*)kbuf;            // alias: spatial K bf16
    u16*   vb16   = (u16*)vbuf;            // alias: spatial V bf16
    // total ws use ~25.9 MB

    CvtArgs ca;
    const void* srcs[17] = {d_in[2], d_in[3], d_in[4], d_in[5], d_in[6], d_in[7],
                            d_in[8], d_in[9], d_in[10], d_in[11], d_in[12], d_in[13],
                            d_in[14], d_in[15], d_in[16], d_in[17], d_in[0]};
    float* dsts[17] = {Win_f, bin_f, Wqs_f, bqs_f, Wks_f, bks_f, Wvs_f, bvs_f,
                       Wqt_f, bqt_f, Wkt_f, bkt_f, Wvt_f, bvt_f, Wout_f, bout_f, xf};
    int    ns[17]   = {192, 64, 8192, 128, 8192, 128, 8192, 128,
                       8192, 128, 8192, 128, 8192, 128, 192, 3, XELEMS};
    for (int i = 0; i < 17; ++i) { ca.src[i] = srcs[i]; ca.dst[i] = dsts[i]; ca.n[i] = ns[i]; }

    (void)hipMemsetAsync(flag, 0, sizeof(int), stream);
    (void)hipMemsetAsync(maskT, 0, 8192 * sizeof(u32), stream);
    detect_kernel<<<64, 256, 0, stream>>>((const u16*)d_in[0], flag);
    convert_kernel<<<dim3((XELEMS + 255) / 256, 17), 256, 0, stream>>>(ca, flag);
    pack_kernel<<<dim3(48, 2), 256, 0, stream>>>(Wqs_f, bqs_f, Wks_f, bks_f, Wvs_f, bvs_f, wTs, bsp);
    pack_kernel<<<dim3(48, 2), 256, 0, stream>>>(Wqt_f, bqt_f, Wkt_f, bkt_f, Wvt_f, bvt_f, wTt, btp);
    scatter_mask_kernel<<<NEDGE / 256, 256, 0, stream>>>(ei, maskT);
    input_proj_kernel<<<ROWS * HIDN / 256, 256, 0, stream>>>(xf, Win_f, bin_f, hbuf);

    const int GEMM_BLOCKS = ROWS / 32;                       // 768
    const int ATTN_BLOCKS = BB * SS * NHEADS * NNODE / 256;  // 768 (temporal)
    for (int l = 0; l < NLAY; ++l) {
        // spatial
        qkv_gemm_kernel<<<GEMM_BLOCKS, 256, 0, stream>>>(
            hbuf, wTs + l * 12288, bsp + l * 192, qbuf, kbuf, vbuf,
            qb16, kb16, vb16, 1);
        spatial_attn_kernel<<<BB * SS * NHEADS * 2, 256, 0, stream>>>(
            qb16, kb16, vb16, maskT, hbuf);
        // temporal
        qkv_gemm_kernel<<<GEMM_BLOCKS, 256, 0, stream>>>(
            hbuf, wTt + l * 12288, btp + l * 192, qbuf, kbuf, vbuf,
            qb16, kb16, vb16, 0);
        temporal_attn_kernel<<<ATTN_BLOCKS, 256, 0, stream>>>(qbuf, kbuf, vbuf, hbuf);
    }
    out_proj_kernel<<<(BB * NNODE * 3 + 255) / 256, 256, 0, stream>>>(
        hbuf, Wout_f, bout_f, d_out, flag);
}